// Round 3
// baseline (130.246 us; speedup 1.0000x reference)
//
#include <hip/hip_runtime.h>
#include <math.h>

// LSTM cell, but the reference returns only h_t[0] (batch row 0) -> [H].
// So we compute just two matvecs (W_ih @ x0, W_hh @ h0) + gate math for 1024
// outputs. Memory-bound on the 32 MB of weights.

#define HDIM 1024
#define DDIM 1024

__global__ __launch_bounds__(256) void lstm_row0_kernel(
    const float* __restrict__ x,      // x_t[0,0,:]   -> first DDIM floats
    const float* __restrict__ hprev,  // h_prev[0,0,:] -> first HDIM floats
    const float* __restrict__ cprev,  // c_prev[0,:]   -> first HDIM floats
    const float* __restrict__ Wih,    // [4H, D] row-major
    const float* __restrict__ Whh,    // [4H, H] row-major
    const float* __restrict__ bih,    // [4H]
    const float* __restrict__ bhh,    // [4H]
    float* __restrict__ out)          // [H]
{
    const int j   = blockIdx.x;    // output index 0..H-1
    const int tid = threadIdx.x;   // 0..255; 4 waves

    // Each thread owns one float4 chunk of the 1024-long vectors.
    const float4 x4 = reinterpret_cast<const float4*>(x)[tid];
    const float4 h4 = reinterpret_cast<const float4*>(hprev)[tid];

    float acc[4];
#pragma unroll
    for (int q = 0; q < 4; ++q) {
        const int gr = j + q * HDIM;   // gate row: i, f, g, o
        const float4 w = reinterpret_cast<const float4*>(Wih + (size_t)gr * DDIM)[tid];
        const float4 v = reinterpret_cast<const float4*>(Whh + (size_t)gr * HDIM)[tid];
        acc[q] = w.x * x4.x + w.y * x4.y + w.z * x4.z + w.w * x4.w
               + v.x * h4.x + v.y * h4.y + v.z * h4.z + v.w * h4.w;
    }

    // Per-wave butterfly reduce (64 lanes).
#pragma unroll
    for (int q = 0; q < 4; ++q) {
#pragma unroll
        for (int off = 32; off > 0; off >>= 1)
            acc[q] += __shfl_down(acc[q], off, 64);
    }

    __shared__ float red[4][4];  // [wave][gate]
    const int wave = tid >> 6;
    const int lane = tid & 63;
    if (lane == 0) {
#pragma unroll
        for (int q = 0; q < 4; ++q) red[wave][q] = acc[q];
    }
    __syncthreads();

    if (tid == 0) {
        float g[4];
#pragma unroll
        for (int q = 0; q < 4; ++q) {
            g[q] = red[0][q] + red[1][q] + red[2][q] + red[3][q]
                 + bih[j + q * HDIM] + bhh[j + q * HDIM];
        }
        const float i_t = 1.0f / (1.0f + __expf(-g[0]));
        const float f_t = 1.0f / (1.0f + __expf(-g[1]));
        const float g_t = tanhf(g[2]);
        const float o_t = 1.0f / (1.0f + __expf(-g[3]));
        const float c_t = f_t * cprev[j] + i_t * g_t;
        out[j] = o_t * tanhf(c_t);
    }
}

extern "C" void kernel_launch(void* const* d_in, const int* in_sizes, int n_in,
                              void* d_out, int out_size, void* d_ws, size_t ws_size,
                              hipStream_t stream) {
    const float* x    = (const float*)d_in[0];  // [1, B, D] -> row 0 is first D
    const float* h    = (const float*)d_in[1];  // [1, B, H] -> row 0 is first H
    const float* c    = (const float*)d_in[2];  // [B, H]    -> row 0 is first H
    const float* Wih  = (const float*)d_in[3];  // [4H, D]
    const float* Whh  = (const float*)d_in[4];  // [4H, H]
    const float* bih  = (const float*)d_in[5];  // [4H]
    const float* bhh  = (const float*)d_in[6];  // [4H]
    float* out = (float*)d_out;                 // [H]

    lstm_row0_kernel<<<HDIM, 256, 0, stream>>>(x, h, c, Wih, Whh, bih, bhh, out);
}